// Round 5
// baseline (222.388 us; speedup 1.0000x reference)
//
#include <hip/hip_runtime.h>
#include <hip/hip_bf16.h>

// Problem dims (fixed)
#define S_ 256
#define BSZ_ 64
#define IN_F_ 1024
#define OUT_F_ 512
#define USER_F_ 512

typedef short short8 __attribute__((ext_vector_type(8)));
typedef float f32x4 __attribute__((ext_vector_type(4)));

__device__ __forceinline__ ushort f2bf(float f) {
  unsigned u = __float_as_uint(f);
  unsigned r = (u + 0x7FFFu + ((u >> 16) & 1u)) >> 16;
  return (ushort)r;
}
__device__ __forceinline__ float bf2f(unsigned hi16) {
  return __uint_as_float(hi16 << 16);
}
__device__ __forceinline__ float sigf(float x) {
  return 1.f / (1.f + __expf(-x));
}
__device__ __forceinline__ float tanh_safe(float x) {
  float ax = fabsf(x);
  float e = __expf(-2.f * ax);
  float r = (1.f - e) / (1.f + e);
  return copysignf(r, x);
}

// async global->LDS, 16B per lane; LDS dest = wave-uniform base + lane*16
__device__ __forceinline__ void gl_lds16(const ushort* g, ushort* l) {
  __builtin_amdgcn_global_load_lds(
      (const __attribute__((address_space(1))) void*)g,
      (__attribute__((address_space(3))) void*)l, 16, 0, 0);
}

// ---------------- prep: weights convert + logit zero (X converts now fused
// into gemm_du's A staging). vec4 ranges: Wd [0,131072) | Wu [..,196608) |
// W [..,262144) | zero [..,270336)
__global__ void prep(const float* __restrict__ Wd, const float* __restrict__ Wu,
                     const float* __restrict__ W,
                     ushort* __restrict__ Wd_bf, ushort* __restrict__ Wu_bf,
                     ushort* __restrict__ W_bf, float* __restrict__ rowlog) {
  int i = blockIdx.x * 256 + threadIdx.x;
  if (i < 131072) {
    float4 v = ((const float4*)Wd)[i];
    ushort4 o; o.x = f2bf(v.x); o.y = f2bf(v.y); o.z = f2bf(v.z); o.w = f2bf(v.w);
    ((ushort4*)Wd_bf)[i] = o;
  } else if (i < 196608) {
    int j = i - 131072;
    float4 v = ((const float4*)Wu)[j];
    ushort4 o; o.x = f2bf(v.x); o.y = f2bf(v.y); o.z = f2bf(v.z); o.w = f2bf(v.w);
    ((ushort4*)Wu_bf)[j] = o;
  } else if (i < 262144) {
    int j = i - 196608;  // W straight convert (coalesced; consumed row-major)
    float4 v = ((const float4*)W)[j];
    ushort4 o; o.x = f2bf(v.x); o.y = f2bf(v.y); o.z = f2bf(v.z); o.w = f2bf(v.w);
    ((ushort4*)W_bf)[j] = o;
  } else {
    int j = i - 262144;  // zero rowlog+collog (contiguous 32768 floats)
    ((float4*)rowlog)[j] = float4{0.f, 0.f, 0.f, 0.f};
  }
}

// ---------------- tile staging ----------------
// LDS row stride 64 shorts; 16B-chunk c of row r at phys slot c^(r&7).
// 4-wave variant: wave w stages rows [w*ROWS/4, (w+1)*ROWS/4)
template <int ROWS>
__device__ __forceinline__ void stage_tile(const ushort* __restrict__ g, int K,
                                           ushort* lds, int w, int lane) {
  const int rin = lane >> 3;  // 0..7
  const int c = lane & 7;     // 16B chunk slot within row
#pragma unroll
  for (int i = 0; i < ROWS / 32; ++i) {
    int r = w * (ROWS / 4) + i * 8 + rin;
    int gc = c ^ (r & 7);
    gl_lds16(g + (long)r * K + gc * 8, lds + w * (ROWS / 4) * 64 + i * 512);
  }
}
// 8-wave variant (512-thread blocks): wave w stages rows [w*16, w*16+16)
__device__ __forceinline__ void stage_tile8w(const ushort* __restrict__ g, int K,
                                             ushort* lds, int w, int lane) {
  const int rin = lane >> 3, c = lane & 7;
#pragma unroll
  for (int i = 0; i < 2; ++i) {
    int r = w * 16 + i * 8 + rin;
    int gc = c ^ (r & 7);
    gl_lds16(g + (long)r * K + gc * 8, lds + w * 1024 + i * 512);
  }
}

// fp32 A reg-staging (fused bf16 convert). Thread t covers row r=t>>2 (of
// 128), 16-float segment seg=t&3 of the 64-col K-slab.
__device__ __forceinline__ void ldA_f32(const float* __restrict__ X, int K,
                                        int k, int t, float4 v[4]) {
  const int r = t >> 2, seg = t & 3;
  const float4* p = (const float4*)(X + (long)r * K + k * 64 + seg * 16);
  v[0] = p[0]; v[1] = p[1]; v[2] = p[2]; v[3] = p[3];
}
// convert + ds_write into the SAME swizzled layout frag() reads.
__device__ __forceinline__ void wrA_bf(ushort* lds, int t, const float4 v[4]) {
  const int r = t >> 2, seg = t & 3;
  const int cc0 = seg * 2;
  const int p0 = cc0 ^ (r & 7), p1 = (cc0 + 1) ^ (r & 7);
  short8 a, b;
  a[0] = (short)f2bf(v[0].x); a[1] = (short)f2bf(v[0].y);
  a[2] = (short)f2bf(v[0].z); a[3] = (short)f2bf(v[0].w);
  a[4] = (short)f2bf(v[1].x); a[5] = (short)f2bf(v[1].y);
  a[6] = (short)f2bf(v[1].z); a[7] = (short)f2bf(v[1].w);
  b[0] = (short)f2bf(v[2].x); b[1] = (short)f2bf(v[2].y);
  b[2] = (short)f2bf(v[2].z); b[3] = (short)f2bf(v[2].w);
  b[4] = (short)f2bf(v[3].x); b[5] = (short)f2bf(v[3].y);
  b[6] = (short)f2bf(v[3].z); b[7] = (short)f2bf(v[3].w);
  *(short8*)(lds + r * 64 + p0 * 8) = a;
  *(short8*)(lds + r * 64 + p1 * 8) = b;
}

__device__ __forceinline__ short8 frag(const ushort* lds, int row, int kk, int q) {
  int pc = (kk * 4 + q) ^ (row & 7);
  return *(const short8*)(lds + row * 64 + pc * 8);
}

// ---------------- compute steps ----------------
// 8 waves as 2x4 (wave tile 64x32): acc[4][2]
__device__ __forceinline__ void compute8w(const ushort* As, const ushort* Bs,
                                          f32x4 acc[4][2], int wr, int wc,
                                          int mlane, int q) {
#pragma unroll
  for (int kk = 0; kk < 2; ++kk) {
    short8 af[4], bfr[2];
#pragma unroll
    for (int r = 0; r < 4; ++r) af[r] = frag(As, wr * 64 + r * 16 + mlane, kk, q);
#pragma unroll
    for (int c = 0; c < 2; ++c) bfr[c] = frag(Bs, wc * 32 + c * 16 + mlane, kk, q);
#pragma unroll
    for (int r = 0; r < 4; ++r)
#pragma unroll
      for (int c = 0; c < 2; ++c)
        acc[r][c] = __builtin_amdgcn_mfma_f32_16x16x32_bf16(af[r], bfr[c], acc[r][c], 0, 0, 0);
  }
}
// 4 waves as 2x2 (wave tile 64x64): acc[4][4] (m97 shape: 32 MFMA/step)
__device__ __forceinline__ void compute4w(const ushort* As, const ushort* Bs,
                                          f32x4 acc[4][4], int wr, int wc,
                                          int mlane, int q) {
#pragma unroll
  for (int kk = 0; kk < 2; ++kk) {
    short8 af[4], bfr[4];
#pragma unroll
    for (int r = 0; r < 4; ++r) af[r] = frag(As, wr * 64 + r * 16 + mlane, kk, q);
#pragma unroll
    for (int c = 0; c < 4; ++c) bfr[c] = frag(Bs, wc * 64 + c * 16 + mlane, kk, q);
#pragma unroll
    for (int r = 0; r < 4; ++r)
#pragma unroll
      for (int c = 0; c < 4; ++c)
        acc[r][c] = __builtin_amdgcn_mfma_f32_16x16x32_bf16(af[r], bfr[c], acc[r][c], 0, 0, 0);
  }
}

#define ACC_ZERO2(a)                            \
  _Pragma("unroll") for (int r = 0; r < 4; ++r) \
  _Pragma("unroll") for (int c = 0; c < 2; ++c) { \
    a[r][c][0] = 0.f; a[r][c][1] = 0.f; a[r][c][2] = 0.f; a[r][c][3] = 0.f; }
#define ACC_ZERO4(a)                            \
  _Pragma("unroll") for (int r = 0; r < 4; ++r) \
  _Pragma("unroll") for (int c = 0; c < 4; ++c) { \
    a[r][c][0] = 0.f; a[r][c][1] = 0.f; a[r][c][2] = 0.f; a[r][c][3] = 0.f; }

// ---------------- 2-phase dbuf K-loops ------------------
// A from fp32 global via regs (fused convert), B via global_load_lds.
// Per step: issue A(k+1) fp32 loads FIRST (consuming them then needs only
// vmcnt<=2, B's gload_lds stays in flight), prefetch B(k+1), compute buf,
// then cvt+ds_write A(k+1) after the MFMAs; ONE barrier per step drains all.
template <int NSTEP>
__device__ __forceinline__ void loop8w_f32A(const float* __restrict__ Xf,
                                            const ushort* __restrict__ B, int K,
                                            ushort* sm, f32x4 acc[4][2], int tid,
                                            int w, int lane, int wr, int wc,
                                            int mlane, int q) {
  float4 av[4];
  ldA_f32(Xf, K, 0, tid, av);
  stage_tile8w(B, K, sm + 8192, w, lane);
  wrA_bf(sm, tid, av);
  __syncthreads();
  int cur = 0;
#pragma unroll 1
  for (int k = 0; k < NSTEP; ++k) {
    ushort* dst = sm + (cur ^ 1) * 16384;
    if (k + 1 < NSTEP) {
      ldA_f32(Xf, K, k + 1, tid, av);                      // issue early
      stage_tile8w(B + (k + 1) * 64, K, dst + 8192, w, lane);
    }
    const ushort* Asc = sm + cur * 16384;
    compute8w(Asc, Asc + 8192, acc, wr, wc, mlane, q);
    if (k + 1 < NSTEP) wrA_bf(dst, tid, av);               // cvt+write late
    __syncthreads();
    cur ^= 1;
  }
}
template <int NSTEP>
__device__ __forceinline__ void loop4w(const ushort* __restrict__ A,
                                       const ushort* __restrict__ B, int K,
                                       ushort* sm, f32x4 acc[4][4], int w,
                                       int lane, int wr, int wc, int mlane, int q) {
  stage_tile<128>(A, K, sm, w, lane);
  stage_tile<128>(B, K, sm + 8192, w, lane);
  __syncthreads();
  int cur = 0;
#pragma unroll 1
  for (int k = 0; k < NSTEP; ++k) {
    if (k + 1 < NSTEP) {
      ushort* dst = sm + (cur ^ 1) * 16384;
      stage_tile<128>(A + (k + 1) * 64, K, dst, w, lane);
      stage_tile<128>(B + (k + 1) * 64, K, dst + 8192, w, lane);
    }
    const ushort* Asc = sm + cur * 16384;
    compute4w(Asc, Asc + 8192, acc, wr, wc, mlane, q);
    __syncthreads();
    cur ^= 1;
  }
}

// ---------------- fused d/u GEMM + gating: fp32 A in, bf16 out -------------
// 8 waves as 2x4; dual acc[4][2]; X converts fused into A staging.
__global__ __launch_bounds__(512, 4) void gemm_du(
    const float* __restrict__ Xd, const ushort* __restrict__ Wd,
    const float* __restrict__ bd,
    const float* __restrict__ Xu, const ushort* __restrict__ Wu,
    const float* __restrict__ bu,
    ushort* __restrict__ dg, ushort* __restrict__ ug) {
  __shared__ ushort sm[32768];  // 64KB: buf0 [As|Bs], buf1 [As|Bs]
  const int i = blockIdx.x;
  const int xcd = i & 7, j = i >> 3;           // j in [0,64)
  const int by = xcd * 16 + (j >> 2), bx = j & 3;
  const int tid = threadIdx.x, lane = tid & 63, w = tid >> 6;
  const int wr = w >> 2, wc = w & 3, mlane = lane & 15, q = lane >> 4;
  const int m0 = by * 128, n0 = bx * 128;

  f32x4 accd[4][2]; ACC_ZERO2(accd);
  loop8w_f32A<16>(Xd + (long)m0 * 1024, Wd + (long)n0 * 1024, 1024, sm, accd,
                  tid, w, lane, wr, wc, mlane, q);
  f32x4 accu[4][2]; ACC_ZERO2(accu);
  loop8w_f32A<8>(Xu + (long)m0 * 512, Wu + (long)n0 * 512, 512, sm, accu,
                 tid, w, lane, wr, wc, mlane, q);

#pragma unroll
  for (int c = 0; c < 2; ++c) {
    const int gn = n0 + wc * 32 + c * 16 + mlane;
    const float bdv = bd[gn], buv = bu[gn];
#pragma unroll
    for (int r = 0; r < 4; ++r)
#pragma unroll
      for (int ii = 0; ii < 4; ++ii) {
        const int gm = m0 + wr * 64 + r * 16 + q * 4 + ii;
        const long idx = (long)gm * OUT_F_ + gn;
        float dp = accd[r][c][ii] + bdv;
        float up = accu[r][c][ii] + buv;
        float dgv = dp * sigf(up);
        float ugv = up * sigf(dgv);
        dg[idx] = f2bf(dgv);
        ug[idx] = f2bf(ugv);
      }
  }
}

// ---------------- v = ug . W^T : 128x128 2-phase dbuf, 256 threads ----------
// v[r,d] = sum_e ug[r,e]*W[d,e]  (W row-major consumed directly as B^T form)
__global__ __launch_bounds__(256, 2) void gemm_v(
    const ushort* __restrict__ ug, const ushort* __restrict__ Wb,
    ushort* __restrict__ v) {
  __shared__ ushort sm[32768];  // 64KB dbuf
  const int i = blockIdx.x;
  const int xcd = i & 7, j = i >> 3;
  const int by = xcd * 16 + (j >> 2), bx = j & 3;
  const int tid = threadIdx.x, lane = tid & 63, w = tid >> 6;
  const int wr = w >> 1, wc = w & 1, mlane = lane & 15, q = lane >> 4;
  const int m0 = by * 128, n0 = bx * 128;

  f32x4 acc[4][4]; ACC_ZERO4(acc);
  loop4w<8>(ug + (long)m0 * 512, Wb + (long)n0 * 512, 512, sm, acc,
            w, lane, wr, wc, mlane, q);
#pragma unroll
  for (int c = 0; c < 4; ++c) {
    const int gn = n0 + wc * 64 + c * 16 + mlane;
#pragma unroll
    for (int r = 0; r < 4; ++r)
#pragma unroll
      for (int ii = 0; ii < 4; ++ii) {
        const int gm = m0 + wr * 64 + r * 16 + q * 4 + ii;
        v[(long)gm * OUT_F_ + gn] = f2bf(acc[r][c][ii]);
      }
  }
}

// ---------------- att = tanh(dg . v^T) + row/col reductions -----------------
// att[s,r] = sum_d dg[s,d]*v[r,d]; per batch 2x2 blocks of 128x128; att
// never touches HBM — tanh'd tile reduces into rowlog/collog via atomics.
__global__ __launch_bounds__(256, 2) void att(
    const ushort* __restrict__ dgp, const ushort* __restrict__ v,
    float* __restrict__ rowlog, float* __restrict__ collog) {
  __shared__ ushort sm[32768];  // 64KB dbuf
  const int i = blockIdx.x;
  const int xcd = i & 7, j = i >> 3;           // j in [0,32)
  const int b = xcd * 8 + (j >> 2);            // 8 batches per XCD: L2 locality
  const int mt = (j >> 1) & 1, nt = j & 1;
  const int tid = threadIdx.x, lane = tid & 63, w = tid >> 6;
  const int wr = w >> 1, wc = w & 1, mlane = lane & 15, q = lane >> 4;

  f32x4 acc[4][4]; ACC_ZERO4(acc);
  loop4w<8>(dgp + ((long)b * S_ + mt * 128) * 512,
            v + ((long)b * S_ + nt * 128) * 512, 512, sm, acc,
            w, lane, wr, wc, mlane, q);

  // tanh + reductions. row (s) = mt*128 + wr*64 + r*16 + q*4 + ii
  //                    col (r) = nt*128 + wc*64 + c*16 + mlane
  float rs[16], cs[4];
#pragma unroll
  for (int x = 0; x < 16; ++x) rs[x] = 0.f;
#pragma unroll
  for (int c = 0; c < 4; ++c) cs[c] = 0.f;
#pragma unroll
  for (int r = 0; r < 4; ++r)
#pragma unroll
    for (int c = 0; c < 4; ++c)
#pragma unroll
      for (int ii = 0; ii < 4; ++ii) {
        float vv = tanh_safe(acc[r][c][ii]);
        rs[r * 4 + ii] += vv;
        cs[c] += vv;
      }
#pragma unroll
  for (int m = 1; m < 16; m <<= 1)
#pragma unroll
    for (int x = 0; x < 16; ++x) rs[x] += __shfl_xor(rs[x], m, 64);
#pragma unroll
  for (int m = 16; m < 64; m <<= 1)
#pragma unroll
    for (int c = 0; c < 4; ++c) cs[c] += __shfl_xor(cs[c], m, 64);

  const int s0 = mt * 128 + wr * 64;
  const int r0 = nt * 128 + wc * 64;
  if (mlane == 0) {
#pragma unroll
    for (int x = 0; x < 16; ++x)
      atomicAdd(&rowlog[b * S_ + s0 + (x >> 2) * 16 + q * 4 + (x & 3)], rs[x]);
  }
  if (q == 0) {
#pragma unroll
    for (int c = 0; c < 4; ++c)
      atomicAdd(&collog[b * S_ + r0 + c * 16 + mlane], cs[c]);
  }
}

// ---------------- finalize: softmax + weighted sums, 4x parallel -------------
__device__ __forceinline__ float block_max(float v, float* buf, int tid) {
  buf[tid] = v; __syncthreads();
  for (int s = 128; s > 0; s >>= 1) {
    if (tid < s) buf[tid] = fmaxf(buf[tid], buf[tid + s]);
    __syncthreads();
  }
  float r = buf[0]; __syncthreads();
  return r;
}
__device__ __forceinline__ float block_sum(float v, float* buf, int tid) {
  buf[tid] = v; __syncthreads();
  for (int s = 128; s > 0; s >>= 1) {
    if (tid < s) buf[tid] = buf[tid] + buf[tid + s];
    __syncthreads();
  }
  float r = buf[0]; __syncthreads();
  return r;
}

__global__ __launch_bounds__(256) void finalize(
    const float* __restrict__ rowlog, const float* __restrict__ collog,
    const ushort* __restrict__ dg, const ushort* __restrict__ ug,
    float* __restrict__ out) {
  __shared__ float sd[S_], su[S_], buf[S_];
  const int b = blockIdx.x >> 2, oc = blockIdx.x & 3;
  const int tid = threadIdx.x;

  const float rowmean = rowlog[b * S_ + tid] * (1.f / (float)S_);
  const float colmean = collog[b * S_ + tid] * (1.f / (float)S_);

  float md = block_max(rowmean, buf, tid);
  float ed = __expf(rowmean - md);
  float sds = block_sum(ed, buf, tid);
  sd[tid] = ed / sds;
  float mu = block_max(colmean, buf, tid);
  float eu = __expf(colmean - mu);
  float sus = block_sum(eu, buf, tid);
  su[tid] = eu / sus;
  __syncthreads();

  const int o = oc * 128 + (tid & 127);
  const ushort* src = (tid < 128) ? dg : ug;
  const float* sw = (tid < 128) ? sd : su;
  const ushort* p = src + (long)b * (S_ * OUT_F_) + o;
  float a = 0.f;
#pragma unroll 8
  for (int s = 0; s < S_; ++s) a += sw[s] * bf2f((unsigned)p[s * OUT_F_]);
  out[((tid < 128) ? 0 : BSZ_ * OUT_F_) + b * OUT_F_ + o] = a;
}

extern "C" void kernel_launch(void* const* d_in, const int* in_sizes, int n_in,
                              void* d_out, int out_size, void* d_ws, size_t ws_size,
                              hipStream_t stream) {
  (void)in_sizes; (void)n_in; (void)out_size; (void)ws_size;
  const float* Xd = (const float*)d_in[0];
  const float* Xu = (const float*)d_in[1];
  const float* Wd = (const float*)d_in[2];
  const float* bd = (const float*)d_in[3];
  const float* Wu = (const float*)d_in[4];
  const float* bu = (const float*)d_in[5];
  const float* W  = (const float*)d_in[6];
  float* out = (float*)d_out;
  char* ws = (char*)d_ws;

  ushort* v_buf  = (ushort*)(ws + 0L);          // 16,777,216 (X copies gone)
  ushort* Wd_bf  = (ushort*)(ws + 50331648L);   //  1,048,576
  ushort* Wu_bf  = (ushort*)(ws + 51380224L);   //    524,288
  ushort* W_bf   = (ushort*)(ws + 51904512L);   //    524,288
  ushort* dg     = (ushort*)(ws + 52428800L);   // 16,777,216
  ushort* ug     = (ushort*)(ws + 69206016L);   // 16,777,216
  float*  rowlog = (float*)(ws + 85983232L);    //     65,536
  float*  collog = (float*)(ws + 86048768L);    //     65,536 (contiguous)

  prep<<<1056, 256, 0, stream>>>(Wd, Wu, W, Wd_bf, Wu_bf, W_bf, rowlog);

  gemm_du<<<512, dim3(512), 0, stream>>>(Xd, Wd_bf, bd, Xu, Wu_bf, bu, dg, ug);
  gemm_v<<<512, dim3(256), 0, stream>>>(ug, W_bf, v_buf);
  att<<<256, dim3(256), 0, stream>>>(dg, v_buf, rowlog, collog);
  finalize<<<256, dim3(256), 0, stream>>>(rowlog, collog, dg, ug, out);
}

// Round 6
// 211.878 us; speedup vs baseline: 1.0496x; 1.0496x over previous
//
#include <hip/hip_runtime.h>
#include <hip/hip_bf16.h>

// Problem dims (fixed)
#define S_ 256
#define BSZ_ 64
#define IN_F_ 1024
#define OUT_F_ 512
#define USER_F_ 512

typedef short short8 __attribute__((ext_vector_type(8)));
typedef float f32x4 __attribute__((ext_vector_type(4)));

__device__ __forceinline__ ushort f2bf(float f) {
  unsigned u = __float_as_uint(f);
  unsigned r = (u + 0x7FFFu + ((u >> 16) & 1u)) >> 16;
  return (ushort)r;
}
__device__ __forceinline__ float bf2f(unsigned hi16) {
  return __uint_as_float(hi16 << 16);
}
__device__ __forceinline__ float sigf(float x) {
  return 1.f / (1.f + __expf(-x));
}
__device__ __forceinline__ float tanh_safe(float x) {
  float ax = fabsf(x);
  float e = __expf(-2.f * ax);
  float r = (1.f - e) / (1.f + e);
  return copysignf(r, x);
}

// async global->LDS, 16B per lane; LDS dest = wave-uniform base + lane*16
__device__ __forceinline__ void gl_lds16(const ushort* g, ushort* l) {
  __builtin_amdgcn_global_load_lds(
      (const __attribute__((address_space(1))) void*)g,
      (__attribute__((address_space(3))) void*)l, 16, 0, 0);
}

// ---------------- prep: ALL converts + logit zero in ONE kernel -------------
// ranges (vec4 units, cumulative): Xd [0,4194304) | Xu [..,6291456) |
// Wd [..,6422528) | Wu [..,6488064) | W [..,6553600) | zero [..,6561792)
__global__ void prep(const float* __restrict__ Xd, const float* __restrict__ Xu,
                     const float* __restrict__ Wd, const float* __restrict__ Wu,
                     const float* __restrict__ W,
                     ushort* __restrict__ Xd_bf, ushort* __restrict__ Xu_bf,
                     ushort* __restrict__ Wd_bf, ushort* __restrict__ Wu_bf,
                     ushort* __restrict__ W_bf, float* __restrict__ rowlog) {
  int i = blockIdx.x * 256 + threadIdx.x;
  if (i < 4194304) {
    float4 v = ((const float4*)Xd)[i];
    ushort4 o; o.x = f2bf(v.x); o.y = f2bf(v.y); o.z = f2bf(v.z); o.w = f2bf(v.w);
    ((ushort4*)Xd_bf)[i] = o;
  } else if (i < 6291456) {
    int j = i - 4194304;
    float4 v = ((const float4*)Xu)[j];
    ushort4 o; o.x = f2bf(v.x); o.y = f2bf(v.y); o.z = f2bf(v.z); o.w = f2bf(v.w);
    ((ushort4*)Xu_bf)[j] = o;
  } else if (i < 6422528) {
    int j = i - 6291456;
    float4 v = ((const float4*)Wd)[j];
    ushort4 o; o.x = f2bf(v.x); o.y = f2bf(v.y); o.z = f2bf(v.z); o.w = f2bf(v.w);
    ((ushort4*)Wd_bf)[j] = o;
  } else if (i < 6488064) {
    int j = i - 6422528;
    float4 v = ((const float4*)Wu)[j];
    ushort4 o; o.x = f2bf(v.x); o.y = f2bf(v.y); o.z = f2bf(v.z); o.w = f2bf(v.w);
    ((ushort4*)Wu_bf)[j] = o;
  } else if (i < 6553600) {
    int j = i - 6488064;  // W straight convert (coalesced; consumed row-major)
    float4 v = ((const float4*)W)[j];
    ushort4 o; o.x = f2bf(v.x); o.y = f2bf(v.y); o.z = f2bf(v.z); o.w = f2bf(v.w);
    ((ushort4*)W_bf)[j] = o;
  } else {
    int j = i - 6553600;  // zero rowlog+collog (contiguous 32768 floats)
    ((float4*)rowlog)[j] = float4{0.f, 0.f, 0.f, 0.f};
  }
}

// ---------------- tile staging ----------------
// LDS row stride 64 shorts; 16B-chunk c of row r at phys slot c^(r&7).
// 8-wave variant (512-thread blocks): wave w stages rows [w*16, w*16+16)
__device__ __forceinline__ void stage_tile8w(const ushort* __restrict__ g, int K,
                                             ushort* lds, int w, int lane) {
  const int rin = lane >> 3, c = lane & 7;
#pragma unroll
  for (int i = 0; i < 2; ++i) {
    int r = w * 16 + i * 8 + rin;
    int gc = c ^ (r & 7);
    gl_lds16(g + (long)r * K + gc * 8, lds + w * 1024 + i * 512);
  }
}

__device__ __forceinline__ short8 frag(const ushort* lds, int row, int kk, int q) {
  int pc = (kk * 4 + q) ^ (row & 7);
  return *(const short8*)(lds + row * 64 + pc * 8);
}

// ---------------- compute step: 8 waves as 2x4 (wave tile 64x32), acc[4][2] -
__device__ __forceinline__ void compute8w(const ushort* As, const ushort* Bs,
                                          f32x4 acc[4][2], int wr, int wc,
                                          int mlane, int q) {
#pragma unroll
  for (int kk = 0; kk < 2; ++kk) {
    short8 af[4], bfr[2];
#pragma unroll
    for (int r = 0; r < 4; ++r) af[r] = frag(As, wr * 64 + r * 16 + mlane, kk, q);
#pragma unroll
    for (int c = 0; c < 2; ++c) bfr[c] = frag(Bs, wc * 32 + c * 16 + mlane, kk, q);
#pragma unroll
    for (int r = 0; r < 4; ++r)
#pragma unroll
      for (int c = 0; c < 2; ++c)
        acc[r][c] = __builtin_amdgcn_mfma_f32_16x16x32_bf16(af[r], bfr[c], acc[r][c], 0, 0, 0);
  }
}

#define ACC_ZERO2(a)                            \
  _Pragma("unroll") for (int r = 0; r < 4; ++r) \
  _Pragma("unroll") for (int c = 0; c < 2; ++c) { \
    a[r][c][0] = 0.f; a[r][c][1] = 0.f; a[r][c][2] = 0.f; a[r][c][3] = 0.f; }

// ---------------- 2-phase dbuf K-loop (R4-proven) ---------------------------
// prologue stages tile 0; per step: prefetch k+1 into buf^1, compute buf,
// ONE barrier (implicit vmcnt(0)+lgkmcnt(0) drain covers stage + ds_reads).
template <int NSTEP>
__device__ __forceinline__ void loop8w(const ushort* __restrict__ A,
                                       const ushort* __restrict__ B, int K,
                                       ushort* sm, f32x4 acc[4][2], int w,
                                       int lane, int wr, int wc, int mlane, int q) {
  stage_tile8w(A, K, sm, w, lane);
  stage_tile8w(B, K, sm + 8192, w, lane);
  __syncthreads();
  int cur = 0;
#pragma unroll 1
  for (int k = 0; k < NSTEP; ++k) {
    if (k + 1 < NSTEP) {
      ushort* dst = sm + (cur ^ 1) * 16384;
      stage_tile8w(A + (k + 1) * 64, K, dst, w, lane);
      stage_tile8w(B + (k + 1) * 64, K, dst + 8192, w, lane);
    }
    const ushort* Asc = sm + cur * 16384;
    compute8w(Asc, Asc + 8192, acc, wr, wc, mlane, q);
    __syncthreads();
    cur ^= 1;
  }
}

// ---------------- fused d/u GEMM + gating: 128x128, 2-phase dbuf (R4) ------
__global__ __launch_bounds__(512, 4) void gemm_du(
    const ushort* __restrict__ Xd, const ushort* __restrict__ Wd,
    const float* __restrict__ bd,
    const ushort* __restrict__ Xu, const ushort* __restrict__ Wu,
    const float* __restrict__ bu,
    ushort* __restrict__ dg, ushort* __restrict__ ug) {
  __shared__ ushort sm[32768];  // 64KB: buf0 [As|Bs], buf1 [As|Bs]
  const int i = blockIdx.x;
  const int xcd = i & 7, j = i >> 3;           // j in [0,64)
  const int by = xcd * 16 + (j >> 2), bx = j & 3;
  const int tid = threadIdx.x, lane = tid & 63, w = tid >> 6;
  const int wr = w >> 2, wc = w & 3, mlane = lane & 15, q = lane >> 4;
  const int m0 = by * 128, n0 = bx * 128;

  f32x4 accd[4][2]; ACC_ZERO2(accd);
  loop8w<16>(Xd + (long)m0 * 1024, Wd + (long)n0 * 1024, 1024, sm, accd,
             w, lane, wr, wc, mlane, q);
  f32x4 accu[4][2]; ACC_ZERO2(accu);
  loop8w<8>(Xu + (long)m0 * 512, Wu + (long)n0 * 512, 512, sm, accu,
            w, lane, wr, wc, mlane, q);

#pragma unroll
  for (int c = 0; c < 2; ++c) {
    const int gn = n0 + wc * 32 + c * 16 + mlane;
    const float bdv = bd[gn], buv = bu[gn];
#pragma unroll
    for (int r = 0; r < 4; ++r)
#pragma unroll
      for (int ii = 0; ii < 4; ++ii) {
        const int gm = m0 + wr * 64 + r * 16 + q * 4 + ii;
        const long idx = (long)gm * OUT_F_ + gn;
        float dp = accd[r][c][ii] + bdv;
        float up = accu[r][c][ii] + buv;
        float dgv = dp * sigf(up);
        float ugv = up * sigf(dgv);
        dg[idx] = f2bf(dgv);
        ug[idx] = f2bf(ugv);
      }
  }
}

// ---------------- v = ug . W^T : 128x128, 8-wave (4 waves/SIMD) -------------
// v[r,d] = sum_e ug[r,e]*W[d,e]  (W row-major consumed directly as B^T form)
__global__ __launch_bounds__(512, 4) void gemm_v(
    const ushort* __restrict__ ug, const ushort* __restrict__ Wb,
    ushort* __restrict__ v) {
  __shared__ ushort sm[32768];  // 64KB dbuf
  const int i = blockIdx.x;
  const int xcd = i & 7, j = i >> 3;
  const int by = xcd * 16 + (j >> 2), bx = j & 3;
  const int tid = threadIdx.x, lane = tid & 63, w = tid >> 6;
  const int wr = w >> 2, wc = w & 3, mlane = lane & 15, q = lane >> 4;
  const int m0 = by * 128, n0 = bx * 128;

  f32x4 acc[4][2]; ACC_ZERO2(acc);
  loop8w<8>(ug + (long)m0 * 512, Wb + (long)n0 * 512, 512, sm, acc,
            w, lane, wr, wc, mlane, q);
#pragma unroll
  for (int c = 0; c < 2; ++c) {
    const int gn = n0 + wc * 32 + c * 16 + mlane;
#pragma unroll
    for (int r = 0; r < 4; ++r)
#pragma unroll
      for (int ii = 0; ii < 4; ++ii) {
        const int gm = m0 + wr * 64 + r * 16 + q * 4 + ii;
        v[(long)gm * OUT_F_ + gn] = f2bf(acc[r][c][ii]);
      }
  }
}

// ---------------- att = tanh(dg . v^T) + row/col reductions, 8-wave ---------
// att[s,r] = sum_d dg[s,d]*v[r,d]; per batch 2x2 blocks of 128x128; att
// never touches HBM — tanh'd tile reduces into rowlog/collog via atomics.
__global__ __launch_bounds__(512, 4) void att(
    const ushort* __restrict__ dgp, const ushort* __restrict__ v,
    float* __restrict__ rowlog, float* __restrict__ collog) {
  __shared__ ushort sm[32768];  // 64KB dbuf
  const int i = blockIdx.x;
  const int xcd = i & 7, j = i >> 3;           // j in [0,32)
  const int b = xcd * 8 + (j >> 2);            // 8 batches per XCD: L2 locality
  const int mt = (j >> 1) & 1, nt = j & 1;
  const int tid = threadIdx.x, lane = tid & 63, w = tid >> 6;
  const int wr = w >> 2, wc = w & 3, mlane = lane & 15, q = lane >> 4;

  f32x4 acc[4][2]; ACC_ZERO2(acc);
  loop8w<8>(dgp + ((long)b * S_ + mt * 128) * 512,
            v + ((long)b * S_ + nt * 128) * 512, 512, sm, acc,
            w, lane, wr, wc, mlane, q);

  // tanh + reductions. row (s) = mt*128 + wr*64 + r*16 + q*4 + ii
  //                    col (r) = nt*128 + wc*32 + c*16 + mlane
  float rs[16], cs[2];
#pragma unroll
  for (int x = 0; x < 16; ++x) rs[x] = 0.f;
#pragma unroll
  for (int c = 0; c < 2; ++c) cs[c] = 0.f;
#pragma unroll
  for (int r = 0; r < 4; ++r)
#pragma unroll
    for (int c = 0; c < 2; ++c)
#pragma unroll
      for (int ii = 0; ii < 4; ++ii) {
        float vv = tanh_safe(acc[r][c][ii]);
        rs[r * 4 + ii] += vv;
        cs[c] += vv;
      }
  // rs: sum over the wave's 32 cols -> reduce across mlane (lanes w/ same q)
#pragma unroll
  for (int m = 1; m < 16; m <<= 1)
#pragma unroll
    for (int x = 0; x < 16; ++x) rs[x] += __shfl_xor(rs[x], m, 64);
  // cs: sum over the wave's 64 rows -> reduce across q (lanes w/ same mlane)
#pragma unroll
  for (int m = 16; m < 64; m <<= 1)
#pragma unroll
    for (int c = 0; c < 2; ++c) cs[c] += __shfl_xor(cs[c], m, 64);

  const int s0 = mt * 128 + wr * 64;
  const int r0 = nt * 128 + wc * 32;
  if (mlane == 0) {
#pragma unroll
    for (int x = 0; x < 16; ++x)
      atomicAdd(&rowlog[b * S_ + s0 + (x >> 2) * 16 + q * 4 + (x & 3)], rs[x]);
  }
  if (q == 0) {
#pragma unroll
    for (int c = 0; c < 2; ++c)
      atomicAdd(&collog[b * S_ + r0 + c * 16 + mlane], cs[c]);
  }
}

// ---------------- finalize: softmax + weighted sums, 4x parallel -------------
__device__ __forceinline__ float block_max(float v, float* buf, int tid) {
  buf[tid] = v; __syncthreads();
  for (int s = 128; s > 0; s >>= 1) {
    if (tid < s) buf[tid] = fmaxf(buf[tid], buf[tid + s]);
    __syncthreads();
  }
  float r = buf[0]; __syncthreads();
  return r;
}
__device__ __forceinline__ float block_sum(float v, float* buf, int tid) {
  buf[tid] = v; __syncthreads();
  for (int s = 128; s > 0; s >>= 1) {
    if (tid < s) buf[tid] = buf[tid] + buf[tid + s];
    __syncthreads();
  }
  float r = buf[0]; __syncthreads();
  return r;
}

__global__ __launch_bounds__(256) void finalize(
    const float* __restrict__ rowlog, const float* __restrict__ collog,
    const ushort* __restrict__ dg, const ushort* __restrict__ ug,
    float* __restrict__ out) {
  __shared__ float sd[S_], su[S_], buf[S_];
  const int b = blockIdx.x >> 2, oc = blockIdx.x & 3;
  const int tid = threadIdx.x;

  const float rowmean = rowlog[b * S_ + tid] * (1.f / (float)S_);
  const float colmean = collog[b * S_ + tid] * (1.f / (float)S_);

  float md = block_max(rowmean, buf, tid);
  float ed = __expf(rowmean - md);
  float sds = block_sum(ed, buf, tid);
  sd[tid] = ed / sds;
  float mu = block_max(colmean, buf, tid);
  float eu = __expf(colmean - mu);
  float sus = block_sum(eu, buf, tid);
  su[tid] = eu / sus;
  __syncthreads();

  const int o = oc * 128 + (tid & 127);
  const ushort* src = (tid < 128) ? dg : ug;
  const float* sw = (tid < 128) ? sd : su;
  const ushort* p = src + (long)b * (S_ * OUT_F_) + o;
  float a = 0.f;
#pragma unroll 8
  for (int s = 0; s < S_; ++s) a += sw[s] * bf2f((unsigned)p[s * OUT_F_]);
  out[((tid < 128) ? 0 : BSZ_ * OUT_F_) + b * OUT_F_ + o] = a;
}

extern "C" void kernel_launch(void* const* d_in, const int* in_sizes, int n_in,
                              void* d_out, int out_size, void* d_ws, size_t ws_size,
                              hipStream_t stream) {
  (void)in_sizes; (void)n_in; (void)out_size; (void)ws_size;
  const float* Xd = (const float*)d_in[0];
  const float* Xu = (const float*)d_in[1];
  const float* Wd = (const float*)d_in[2];
  const float* bd = (const float*)d_in[3];
  const float* Wu = (const float*)d_in[4];
  const float* bu = (const float*)d_in[5];
  const float* W  = (const float*)d_in[6];
  float* out = (float*)d_out;
  char* ws = (char*)d_ws;

  ushort* Xd_bf  = (ushort*)(ws + 0L);          // 33,554,432
  ushort* Xu_bf  = (ushort*)(ws + 33554432L);   // 16,777,216
  ushort* Wd_bf  = (ushort*)(ws + 50331648L);   //  1,048,576
  ushort* Wu_bf  = (ushort*)(ws + 51380224L);   //    524,288
  ushort* W_bf   = (ushort*)(ws + 51904512L);   //    524,288
  ushort* dg     = (ushort*)(ws + 52428800L);   // 16,777,216
  ushort* ug     = (ushort*)(ws + 69206016L);   // 16,777,216
  float*  rowlog = (float*)(ws + 85983232L);    //     65,536
  float*  collog = (float*)(ws + 86048768L);    //     65,536 (contiguous)
  ushort* v_buf  = Xd_bf;  // Xd_bf dead after gemm_du; reuse for v (16.7 MB)

  prep<<<25632, 256, 0, stream>>>(Xd, Xu, Wd, Wu, W, Xd_bf, Xu_bf,
                                  Wd_bf, Wu_bf, W_bf, rowlog);

  gemm_du<<<512, dim3(512), 0, stream>>>(Xd_bf, Wd_bf, bd, Xu_bf, Wu_bf, bu, dg, ug);
  gemm_v<<<512, dim3(512), 0, stream>>>(ug, W_bf, v_buf);
  att<<<256, dim3(512), 0, stream>>>(dg, v_buf, rowlog, collog);
  finalize<<<256, dim3(256), 0, stream>>>(rowlog, collog, dg, ug, out);
}

// Round 7
// 209.194 us; speedup vs baseline: 1.0631x; 1.0128x over previous
//
#include <hip/hip_runtime.h>
#include <hip/hip_bf16.h>

// Problem dims (fixed)
#define S_ 256
#define BSZ_ 64
#define IN_F_ 1024
#define OUT_F_ 512
#define USER_F_ 512

typedef short short8 __attribute__((ext_vector_type(8)));
typedef float f32x4 __attribute__((ext_vector_type(4)));

__device__ __forceinline__ ushort f2bf(float f) {
  unsigned u = __float_as_uint(f);
  unsigned r = (u + 0x7FFFu + ((u >> 16) & 1u)) >> 16;
  return (ushort)r;
}
__device__ __forceinline__ float bf2f(unsigned hi16) {
  return __uint_as_float(hi16 << 16);
}
__device__ __forceinline__ float sigf(float x) {
  return 1.f / (1.f + __expf(-x));
}
__device__ __forceinline__ float tanh_safe(float x) {
  float ax = fabsf(x);
  float e = __expf(-2.f * ax);
  float r = (1.f - e) / (1.f + e);
  return copysignf(r, x);
}

// async global->LDS, 16B per lane; LDS dest = wave-uniform base + lane*16
__device__ __forceinline__ void gl_lds16(const ushort* g, ushort* l) {
  __builtin_amdgcn_global_load_lds(
      (const __attribute__((address_space(1))) void*)g,
      (__attribute__((address_space(3))) void*)l, 16, 0, 0);
}

// ---------------- prep: ALL converts + logit zero in ONE kernel -------------
// ranges (vec4 units, cumulative): Xd [0,4194304) | Xu [..,6291456) |
// Wd [..,6422528) | Wu [..,6488064) | W [..,6553600) | zero [..,6561792)
__global__ void prep(const float* __restrict__ Xd, const float* __restrict__ Xu,
                     const float* __restrict__ Wd, const float* __restrict__ Wu,
                     const float* __restrict__ W,
                     ushort* __restrict__ Xd_bf, ushort* __restrict__ Xu_bf,
                     ushort* __restrict__ Wd_bf, ushort* __restrict__ Wu_bf,
                     ushort* __restrict__ W_bf, float* __restrict__ rowlog) {
  int i = blockIdx.x * 256 + threadIdx.x;
  if (i < 4194304) {
    float4 v = ((const float4*)Xd)[i];
    ushort4 o; o.x = f2bf(v.x); o.y = f2bf(v.y); o.z = f2bf(v.z); o.w = f2bf(v.w);
    ((ushort4*)Xd_bf)[i] = o;
  } else if (i < 6291456) {
    int j = i - 4194304;
    float4 v = ((const float4*)Xu)[j];
    ushort4 o; o.x = f2bf(v.x); o.y = f2bf(v.y); o.z = f2bf(v.z); o.w = f2bf(v.w);
    ((ushort4*)Xu_bf)[j] = o;
  } else if (i < 6422528) {
    int j = i - 6291456;
    float4 v = ((const float4*)Wd)[j];
    ushort4 o; o.x = f2bf(v.x); o.y = f2bf(v.y); o.z = f2bf(v.z); o.w = f2bf(v.w);
    ((ushort4*)Wd_bf)[j] = o;
  } else if (i < 6488064) {
    int j = i - 6422528;
    float4 v = ((const float4*)Wu)[j];
    ushort4 o; o.x = f2bf(v.x); o.y = f2bf(v.y); o.z = f2bf(v.z); o.w = f2bf(v.w);
    ((ushort4*)Wu_bf)[j] = o;
  } else if (i < 6553600) {
    int j = i - 6488064;  // W straight convert (coalesced; consumed row-major)
    float4 v = ((const float4*)W)[j];
    ushort4 o; o.x = f2bf(v.x); o.y = f2bf(v.y); o.z = f2bf(v.z); o.w = f2bf(v.w);
    ((ushort4*)W_bf)[j] = o;
  } else {
    int j = i - 6553600;  // zero rowlog+collog (contiguous 32768 floats)
    ((float4*)rowlog)[j] = float4{0.f, 0.f, 0.f, 0.f};
  }
}

// ---------------- tile staging ----------------
// LDS row stride 64 shorts; 16B-chunk c of row r at phys slot c^(r&7).
// 8-wave variant (512-thread blocks): wave w stages rows [w*16, w*16+16)
__device__ __forceinline__ void stage_tile8w(const ushort* __restrict__ g, int K,
                                             ushort* lds, int w, int lane) {
  const int rin = lane >> 3, c = lane & 7;
#pragma unroll
  for (int i = 0; i < 2; ++i) {
    int r = w * 16 + i * 8 + rin;
    int gc = c ^ (r & 7);
    gl_lds16(g + (long)r * K + gc * 8, lds + w * 1024 + i * 512);
  }
}

__device__ __forceinline__ short8 frag(const ushort* lds, int row, int kk, int q) {
  int pc = (kk * 4 + q) ^ (row & 7);
  return *(const short8*)(lds + row * 64 + pc * 8);
}

// ---------------- compute step: 8 waves as 2x4 (wave tile 64x32), acc[4][2] -
__device__ __forceinline__ void compute8w(const ushort* As, const ushort* Bs,
                                          f32x4 acc[4][2], int wr, int wc,
                                          int mlane, int q) {
#pragma unroll
  for (int kk = 0; kk < 2; ++kk) {
    short8 af[4], bfr[2];
#pragma unroll
    for (int r = 0; r < 4; ++r) af[r] = frag(As, wr * 64 + r * 16 + mlane, kk, q);
#pragma unroll
    for (int c = 0; c < 2; ++c) bfr[c] = frag(Bs, wc * 32 + c * 16 + mlane, kk, q);
#pragma unroll
    for (int r = 0; r < 4; ++r)
#pragma unroll
      for (int c = 0; c < 2; ++c)
        acc[r][c] = __builtin_amdgcn_mfma_f32_16x16x32_bf16(af[r], bfr[c], acc[r][c], 0, 0, 0);
  }
}

#define ACC_ZERO2(a)                            \
  _Pragma("unroll") for (int r = 0; r < 4; ++r) \
  _Pragma("unroll") for (int c = 0; c < 2; ++c) { \
    a[r][c][0] = 0.f; a[r][c][1] = 0.f; a[r][c][2] = 0.f; a[r][c][3] = 0.f; }

// ---------------- 2-phase dbuf K-loop with COUNTED vmcnt (T4) ---------------
// Per step: issue the 4 global_load_lds for tile k+1 into buf^1, then
// s_waitcnt vmcnt(4) — drains tile k's loads, keeps tile k+1 IN FLIGHT
// across both barriers — barrier, MFMAs (setprio-wrapped, T5: 2 independent
// blocks/CU give role diversity), barrier (read-complete before overwrite).
// Never vmcnt(0) in the main loop; final iteration drains fully.
// Compiler fences ("" memory clobber) pin ds_reads inside the barrier pair.
template <int NSTEP>
__device__ __forceinline__ void loop8w(const ushort* __restrict__ A,
                                       const ushort* __restrict__ B, int K,
                                       ushort* sm, f32x4 acc[4][2], int w,
                                       int lane, int wr, int wc, int mlane, int q) {
  stage_tile8w(A, K, sm, w, lane);
  stage_tile8w(B, K, sm + 8192, w, lane);
  int cur = 0;
#pragma unroll 1
  for (int k = 0; k < NSTEP; ++k) {
    if (k + 1 < NSTEP) {
      ushort* dst = sm + (cur ^ 1) * 16384;
      stage_tile8w(A + (k + 1) * 64, K, dst, w, lane);
      stage_tile8w(B + (k + 1) * 64, K, dst + 8192, w, lane);
      asm volatile("s_waitcnt vmcnt(4)" ::: "memory");
    } else {
      asm volatile("s_waitcnt vmcnt(0)" ::: "memory");
    }
    __builtin_amdgcn_s_barrier();
    asm volatile("" ::: "memory");  // no ds_read hoists above the barrier
    const ushort* Asc = sm + cur * 16384;
    __builtin_amdgcn_s_setprio(1);
    compute8w(Asc, Asc + 8192, acc, wr, wc, mlane, q);
    __builtin_amdgcn_s_setprio(0);
    asm volatile("" ::: "memory");  // no ds_read sinks below the barrier
    __builtin_amdgcn_s_barrier();
    cur ^= 1;
  }
}

// ---------------- fused d/u GEMM + gating: 128x128, counted-vmcnt dbuf -----
__global__ __launch_bounds__(512, 4) void gemm_du(
    const ushort* __restrict__ Xd, const ushort* __restrict__ Wd,
    const float* __restrict__ bd,
    const ushort* __restrict__ Xu, const ushort* __restrict__ Wu,
    const float* __restrict__ bu,
    ushort* __restrict__ dg, ushort* __restrict__ ug) {
  __shared__ ushort sm[32768];  // 64KB: buf0 [As|Bs], buf1 [As|Bs]
  const int i = blockIdx.x;
  const int xcd = i & 7, j = i >> 3;           // j in [0,64)
  const int by = xcd * 16 + (j >> 2), bx = j & 3;
  const int tid = threadIdx.x, lane = tid & 63, w = tid >> 6;
  const int wr = w >> 2, wc = w & 3, mlane = lane & 15, q = lane >> 4;
  const int m0 = by * 128, n0 = bx * 128;

  f32x4 accd[4][2]; ACC_ZERO2(accd);
  loop8w<16>(Xd + (long)m0 * 1024, Wd + (long)n0 * 1024, 1024, sm, accd,
             w, lane, wr, wc, mlane, q);
  f32x4 accu[4][2]; ACC_ZERO2(accu);
  loop8w<8>(Xu + (long)m0 * 512, Wu + (long)n0 * 512, 512, sm, accu,
            w, lane, wr, wc, mlane, q);

#pragma unroll
  for (int c = 0; c < 2; ++c) {
    const int gn = n0 + wc * 32 + c * 16 + mlane;
    const float bdv = bd[gn], buv = bu[gn];
#pragma unroll
    for (int r = 0; r < 4; ++r)
#pragma unroll
      for (int ii = 0; ii < 4; ++ii) {
        const int gm = m0 + wr * 64 + r * 16 + q * 4 + ii;
        const long idx = (long)gm * OUT_F_ + gn;
        float dp = accd[r][c][ii] + bdv;
        float up = accu[r][c][ii] + buv;
        float dgv = dp * sigf(up);
        float ugv = up * sigf(dgv);
        dg[idx] = f2bf(dgv);
        ug[idx] = f2bf(ugv);
      }
  }
}

// ---------------- v = ug . W^T : 128x128, 8-wave counted-vmcnt --------------
// v[r,d] = sum_e ug[r,e]*W[d,e]  (W row-major consumed directly as B^T form)
__global__ __launch_bounds__(512, 4) void gemm_v(
    const ushort* __restrict__ ug, const ushort* __restrict__ Wb,
    ushort* __restrict__ v) {
  __shared__ ushort sm[32768];  // 64KB dbuf
  const int i = blockIdx.x;
  const int xcd = i & 7, j = i >> 3;
  const int by = xcd * 16 + (j >> 2), bx = j & 3;
  const int tid = threadIdx.x, lane = tid & 63, w = tid >> 6;
  const int wr = w >> 2, wc = w & 3, mlane = lane & 15, q = lane >> 4;
  const int m0 = by * 128, n0 = bx * 128;

  f32x4 acc[4][2]; ACC_ZERO2(acc);
  loop8w<8>(ug + (long)m0 * 512, Wb + (long)n0 * 512, 512, sm, acc,
            w, lane, wr, wc, mlane, q);
#pragma unroll
  for (int c = 0; c < 2; ++c) {
    const int gn = n0 + wc * 32 + c * 16 + mlane;
#pragma unroll
    for (int r = 0; r < 4; ++r)
#pragma unroll
      for (int ii = 0; ii < 4; ++ii) {
        const int gm = m0 + wr * 64 + r * 16 + q * 4 + ii;
        v[(long)gm * OUT_F_ + gn] = f2bf(acc[r][c][ii]);
      }
  }
}

// ---------------- att = tanh(dg . v^T) + row/col reductions, 8-wave ---------
// att[s,r] = sum_d dg[s,d]*v[r,d]; per batch 2x2 blocks of 128x128; att
// never touches HBM — tanh'd tile reduces into rowlog/collog via atomics.
__global__ __launch_bounds__(512, 4) void att(
    const ushort* __restrict__ dgp, const ushort* __restrict__ v,
    float* __restrict__ rowlog, float* __restrict__ collog) {
  __shared__ ushort sm[32768];  // 64KB dbuf
  const int i = blockIdx.x;
  const int xcd = i & 7, j = i >> 3;           // j in [0,32)
  const int b = xcd * 8 + (j >> 2);            // 8 batches per XCD: L2 locality
  const int mt = (j >> 1) & 1, nt = j & 1;
  const int tid = threadIdx.x, lane = tid & 63, w = tid >> 6;
  const int wr = w >> 2, wc = w & 3, mlane = lane & 15, q = lane >> 4;

  f32x4 acc[4][2]; ACC_ZERO2(acc);
  loop8w<8>(dgp + ((long)b * S_ + mt * 128) * 512,
            v + ((long)b * S_ + nt * 128) * 512, 512, sm, acc,
            w, lane, wr, wc, mlane, q);

  // tanh + reductions. row (s) = mt*128 + wr*64 + r*16 + q*4 + ii
  //                    col (r) = nt*128 + wc*32 + c*16 + mlane
  float rs[16], cs[2];
#pragma unroll
  for (int x = 0; x < 16; ++x) rs[x] = 0.f;
#pragma unroll
  for (int c = 0; c < 2; ++c) cs[c] = 0.f;
#pragma unroll
  for (int r = 0; r < 4; ++r)
#pragma unroll
    for (int c = 0; c < 2; ++c)
#pragma unroll
      for (int ii = 0; ii < 4; ++ii) {
        float vv = tanh_safe(acc[r][c][ii]);
        rs[r * 4 + ii] += vv;
        cs[c] += vv;
      }
  // rs: sum over the wave's 32 cols -> reduce across mlane (lanes w/ same q)
#pragma unroll
  for (int m = 1; m < 16; m <<= 1)
#pragma unroll
    for (int x = 0; x < 16; ++x) rs[x] += __shfl_xor(rs[x], m, 64);
  // cs: sum over the wave's 64 rows -> reduce across q (lanes w/ same mlane)
#pragma unroll
  for (int m = 16; m < 64; m <<= 1)
#pragma unroll
    for (int c = 0; c < 2; ++c) cs[c] += __shfl_xor(cs[c], m, 64);

  const int s0 = mt * 128 + wr * 64;
  const int r0 = nt * 128 + wc * 32;
  if (mlane == 0) {
#pragma unroll
    for (int x = 0; x < 16; ++x)
      atomicAdd(&rowlog[b * S_ + s0 + (x >> 2) * 16 + q * 4 + (x & 3)], rs[x]);
  }
  if (q == 0) {
#pragma unroll
    for (int c = 0; c < 2; ++c)
      atomicAdd(&collog[b * S_ + r0 + c * 16 + mlane], cs[c]);
  }
}

// ---------------- finalize: softmax + weighted sums, 4x parallel -------------
__device__ __forceinline__ float block_max(float v, float* buf, int tid) {
  buf[tid] = v; __syncthreads();
  for (int s = 128; s > 0; s >>= 1) {
    if (tid < s) buf[tid] = fmaxf(buf[tid], buf[tid + s]);
    __syncthreads();
  }
  float r = buf[0]; __syncthreads();
  return r;
}
__device__ __forceinline__ float block_sum(float v, float* buf, int tid) {
  buf[tid] = v; __syncthreads();
  for (int s = 128; s > 0; s >>= 1) {
    if (tid < s) buf[tid] = buf[tid] + buf[tid + s];
    __syncthreads();
  }
  float r = buf[0]; __syncthreads();
  return r;
}

__global__ __launch_bounds__(256) void finalize(
    const float* __restrict__ rowlog, const float* __restrict__ collog,
    const ushort* __restrict__ dg, const ushort* __restrict__ ug,
    float* __restrict__ out) {
  __shared__ float sd[S_], su[S_], buf[S_];
  const int b = blockIdx.x >> 2, oc = blockIdx.x & 3;
  const int tid = threadIdx.x;

  const float rowmean = rowlog[b * S_ + tid] * (1.f / (float)S_);
  const float colmean = collog[b * S_ + tid] * (1.f / (float)S_);

  float md = block_max(rowmean, buf, tid);
  float ed = __expf(rowmean - md);
  float sds = block_sum(ed, buf, tid);
  sd[tid] = ed / sds;
  float mu = block_max(colmean, buf, tid);
  float eu = __expf(colmean - mu);
  float sus = block_sum(eu, buf, tid);
  su[tid] = eu / sus;
  __syncthreads();

  const int o = oc * 128 + (tid & 127);
  const ushort* src = (tid < 128) ? dg : ug;
  const float* sw = (tid < 128) ? sd : su;
  const ushort* p = src + (long)b * (S_ * OUT_F_) + o;
  float a = 0.f;
#pragma unroll 8
  for (int s = 0; s < S_; ++s) a += sw[s] * bf2f((unsigned)p[s * OUT_F_]);
  out[((tid < 128) ? 0 : BSZ_ * OUT_F_) + b * OUT_F_ + o] = a;
}

extern "C" void kernel_launch(void* const* d_in, const int* in_sizes, int n_in,
                              void* d_out, int out_size, void* d_ws, size_t ws_size,
                              hipStream_t stream) {
  (void)in_sizes; (void)n_in; (void)out_size; (void)ws_size;
  const float* Xd = (const float*)d_in[0];
  const float* Xu = (const float*)d_in[1];
  const float* Wd = (const float*)d_in[2];
  const float* bd = (const float*)d_in[3];
  const float* Wu = (const float*)d_in[4];
  const float* bu = (const float*)d_in[5];
  const float* W  = (const float*)d_in[6];
  float* out = (float*)d_out;
  char* ws = (char*)d_ws;

  ushort* Xd_bf  = (ushort*)(ws + 0L);          // 33,554,432
  ushort* Xu_bf  = (ushort*)(ws + 33554432L);   // 16,777,216
  ushort* Wd_bf  = (ushort*)(ws + 50331648L);   //  1,048,576
  ushort* Wu_bf  = (ushort*)(ws + 51380224L);   //    524,288
  ushort* W_bf   = (ushort*)(ws + 51904512L);   //    524,288
  ushort* dg     = (ushort*)(ws + 52428800L);   // 16,777,216
  ushort* ug     = (ushort*)(ws + 69206016L);   // 16,777,216
  float*  rowlog = (float*)(ws + 85983232L);    //     65,536
  float*  collog = (float*)(ws + 86048768L);    //     65,536 (contiguous)
  ushort* v_buf  = Xd_bf;  // Xd_bf dead after gemm_du; reuse for v (16.7 MB)

  prep<<<25632, 256, 0, stream>>>(Xd, Xu, Wd, Wu, W, Xd_bf, Xu_bf,
                                  Wd_bf, Wu_bf, W_bf, rowlog);

  gemm_du<<<512, dim3(512), 0, stream>>>(Xd_bf, Wd_bf, bd, Xu_bf, Wu_bf, bu, dg, ug);
  gemm_v<<<512, dim3(512), 0, stream>>>(ug, W_bf, v_buf);
  att<<<256, dim3(512), 0, stream>>>(dg, v_buf, rowlog, collog);
  finalize<<<256, dim3(256), 0, stream>>>(rowlog, collog, dg, ug, out);
}